// Round 1
// baseline (1318.875 us; speedup 1.0000x reference)
//
#include <hip/hip_runtime.h>
#include <hip/hip_bf16.h>
#include <cfloat>

// Problem constants
#define B_   8
#define C_   256
#define CR_  128
#define T_   16
#define HW_  784
#define THW_ 12544           // T_*HW_
#define N_   1024            // B_*CR_
#define KTOP 196

#define BKG 16               // GEMM K-tile

// ---------------------------------------------------------------------------
// Kernel 0: transpose weights to k-major for coalesced LDS staging.
// Wt3[c][o3] (o3 in [0,384): Wq rows 0-127, Wk 128-255, Wv 256-383)
// Wrt[cr][co] (128 x 256)
// ---------------------------------------------------------------------------
__global__ __launch_bounds__(256) void transpose_w(
    const float* __restrict__ Wq, const float* __restrict__ Wk,
    const float* __restrict__ Wv, const float* __restrict__ Wr,
    float* __restrict__ Wt3, float* __restrict__ Wrt)
{
    int idx = blockIdx.x * 256 + threadIdx.x;
    if (idx < 384 * 256) {                      // 98304
        int c = idx / 384, o3 = idx % 384;
        int m = o3 >> 7, r = o3 & 127;
        const float* W = (m == 0) ? Wq : (m == 1) ? Wk : Wv;
        Wt3[idx] = W[r * 256 + c];
    }
    if (idx < 128 * 256) {                      // 32768
        int cr = idx >> 8, co = idx & 255;
        Wrt[idx] = Wr[co * 128 + cr];
    }
}

// ---------------------------------------------------------------------------
// Kernel 1: QKV GEMM.  out[b,o,p] = sum_c W[o,c] x[b,c,p] + bias[o]
// 128x128 tile, BK=16, 8x8 microtile per thread (256 threads).
// grid (98, 3, 8): (p_tile, matrix, batch)
// ---------------------------------------------------------------------------
__global__ __launch_bounds__(256) void gemm_qkv(
    const float* __restrict__ Wt3, const float* __restrict__ x,
    const float* __restrict__ bq, const float* __restrict__ bk,
    const float* __restrict__ bv,
    float* __restrict__ Qb, float* __restrict__ Kb, float* __restrict__ Vb)
{
    const int pt = blockIdx.x;
    const int m  = blockIdx.y;
    const int b  = blockIdx.z;
    const int tid = threadIdx.x;
    const int tx = tid & 15, ty = tid >> 4;
    const int p_base = pt * 128;
    const int o_base = m * 128;

    __shared__ float sA[BKG][128];
    __shared__ float sB[BKG][128];

    float acc[8][8];
#pragma unroll
    for (int i = 0; i < 8; i++)
#pragma unroll
        for (int j = 0; j < 8; j++) acc[i][j] = 0.f;

    const float* xb = x + (size_t)b * C_ * THW_;

    for (int k0 = 0; k0 < 256; k0 += BKG) {
#pragma unroll
        for (int r = 0; r < 2; r++) {
            int idx = tid + 256 * r;             // 0..511
            int kc  = idx >> 5;                  // 0..15
            int o4  = (idx & 31) << 2;           // 0..124
            *(float4*)&sA[kc][o4] =
                *(const float4*)&Wt3[(size_t)(k0 + kc) * 384 + o_base + o4];
            *(float4*)&sB[kc][o4] =
                *(const float4*)&xb[(size_t)(k0 + kc) * THW_ + p_base + o4];
        }
        __syncthreads();
#pragma unroll
        for (int kk = 0; kk < BKG; kk++) {
            float4 a0 = *(const float4*)&sA[kk][ty * 4];
            float4 a1 = *(const float4*)&sA[kk][ty * 4 + 64];
            float4 b0 = *(const float4*)&sB[kk][tx * 4];
            float4 b1 = *(const float4*)&sB[kk][tx * 4 + 64];
            float a[8] = {a0.x, a0.y, a0.z, a0.w, a1.x, a1.y, a1.z, a1.w};
            float bb[8] = {b0.x, b0.y, b0.z, b0.w, b1.x, b1.y, b1.z, b1.w};
#pragma unroll
            for (int i = 0; i < 8; i++)
#pragma unroll
                for (int j = 0; j < 8; j++) acc[i][j] += a[i] * bb[j];
        }
        __syncthreads();
    }

    const float* bias = (m == 0) ? bq : (m == 1) ? bk : bv;
    float* outp       = (m == 0) ? Qb : (m == 1) ? Kb : Vb;
#pragma unroll
    for (int i = 0; i < 8; i++) {
        int cr = ty * 4 + (i & 3) + (i >> 2) * 64;
        float bi = bias[cr];
        size_t rowoff = ((size_t)b * CR_ + cr) * THW_;
#pragma unroll
        for (int jh = 0; jh < 2; jh++) {
            int p = p_base + tx * 4 + jh * 64;
            float4 v;
            v.x = acc[i][jh * 4 + 0] + bi;
            v.y = acc[i][jh * 4 + 1] + bi;
            v.z = acc[i][jh * 4 + 2] + bi;
            v.w = acc[i][jh * 4 + 3] + bi;
            *(float4*)&outp[rowoff + p] = v;
        }
    }
}

// ---------------------------------------------------------------------------
// Kernel 2: per-row descending bitonic sort (784 padded to 1024), keep top 196.
// grid (16384, 2): row, {Q,K}
// ---------------------------------------------------------------------------
__global__ __launch_bounds__(256) void topk_sort(
    const float* __restrict__ Qb, const float* __restrict__ Kb,
    float* __restrict__ Qtk, float* __restrict__ Ktk)
{
    __shared__ float s[1024];
    const int row = blockIdx.x;
    const float* src = ((blockIdx.y == 0) ? Qb : Kb) + (size_t)row * HW_;
    float* dst       = ((blockIdx.y == 0) ? Qtk : Ktk) + (size_t)row * KTOP;
    const int tid = threadIdx.x;

    for (int i = tid; i < 1024; i += 256)
        s[i] = (i < HW_) ? src[i] : -FLT_MAX;
    __syncthreads();

    for (int k = 2; k <= 1024; k <<= 1) {
        for (int j = k >> 1; j > 0; j >>= 1) {
            for (int i = tid; i < 1024; i += 256) {
                int ixj = i ^ j;
                if (ixj > i) {
                    float a = s[i], c = s[ixj];
                    bool up = ((i & k) == 0);      // descending overall
                    if (up ? (a < c) : (a > c)) { s[i] = c; s[ixj] = a; }
                }
            }
            __syncthreads();
        }
    }
    for (int i = tid; i < KTOP; i += 256) dst[i] = s[i];
}

// ---------------------------------------------------------------------------
// Kernel 3: corr[n,t,s] = dot(Qtk[n,t,:], Ktk[n,s,:]) then softmax over s.
// grid (1024), block 256 (one (t,s) pair per thread)
// ---------------------------------------------------------------------------
__global__ __launch_bounds__(256) void corr_softmax(
    const float* __restrict__ Qtk, const float* __restrict__ Ktk,
    float* __restrict__ attn)
{
    const int n = blockIdx.x;
    __shared__ float qs[T_ * KTOP];
    __shared__ float ks[T_ * KTOP];
    __shared__ float cm[T_][T_ + 1];
    __shared__ float mx[T_], sm[T_];
    const int tid = threadIdx.x;

    for (int i = tid; i < T_ * KTOP; i += 256) {
        qs[i] = Qtk[(size_t)n * T_ * KTOP + i];
        ks[i] = Ktk[(size_t)n * T_ * KTOP + i];
    }
    __syncthreads();

    const int t = tid >> 4, sidx = tid & 15;
    const float* qr = &qs[t * KTOP];
    const float* kr = &ks[sidx * KTOP];
    float c = 0.f;
#pragma unroll 4
    for (int i = 0; i < KTOP; i++) c += qr[i] * kr[i];
    cm[t][sidx] = c;
    __syncthreads();

    if (tid < T_) {
        float m = cm[tid][0];
        for (int i = 1; i < T_; i++) m = fmaxf(m, cm[tid][i]);
        mx[tid] = m;
    }
    __syncthreads();
    float e = expf(c - mx[t]);
    cm[t][sidx] = e;
    __syncthreads();
    if (tid < T_) {
        float ssum = 0.f;
        for (int i = 0; i < T_; i++) ssum += cm[tid][i];
        sm[tid] = ssum;
    }
    __syncthreads();
    attn[(size_t)n * 256 + tid] = e / sm[t];
}

// ---------------------------------------------------------------------------
// Kernel 4: y[n,t,p] = sum_s attn[n,t,s] * V[n,s,p]
// grid (7, 1024): p-chunk of 112, n
// ---------------------------------------------------------------------------
__global__ __launch_bounds__(256) void apply_attn(
    const float* __restrict__ attn, const float* __restrict__ V,
    float* __restrict__ y)
{
    const int pc = blockIdx.x;
    const int n  = blockIdx.y;
    __shared__ float at[256];
    __shared__ float vt[T_][112];
    const int tid = threadIdx.x;

    at[tid] = attn[(size_t)n * 256 + tid];
    const int p0 = pc * 112;
    for (int idx = tid; idx < T_ * 112; idx += 256) {
        int s = idx / 112, pp = idx % 112;
        vt[s][pp] = V[(size_t)n * THW_ + s * HW_ + p0 + pp];
    }
    __syncthreads();

    for (int idx = tid; idx < T_ * 112; idx += 256) {
        int t = idx / 112, pp = idx % 112;
        float a = 0.f;
#pragma unroll
        for (int s = 0; s < T_; s++) a += at[t * 16 + s] * vt[s][pp];
        y[(size_t)n * THW_ + t * HW_ + p0 + pp] = a;
    }
}

// ---------------------------------------------------------------------------
// Kernel 5: out[b,co,p] = scale*(sum_cr Wr[co,cr] y[b,cr,p] + br) + shift + x
// grid (98, 2, 8)
// ---------------------------------------------------------------------------
__global__ __launch_bounds__(256) void gemm_recon(
    const float* __restrict__ Wrt, const float* __restrict__ y,
    const float* __restrict__ br, const float* __restrict__ gamma,
    const float* __restrict__ beta, const float* __restrict__ bn_mean,
    const float* __restrict__ bn_var, const float* __restrict__ x,
    float* __restrict__ out)
{
    const int pt = blockIdx.x;
    const int ot = blockIdx.y;
    const int b  = blockIdx.z;
    const int tid = threadIdx.x;
    const int tx = tid & 15, ty = tid >> 4;
    const int p_base = pt * 128;
    const int o_base = ot * 128;

    __shared__ float sA[BKG][128];
    __shared__ float sB[BKG][128];

    float acc[8][8];
#pragma unroll
    for (int i = 0; i < 8; i++)
#pragma unroll
        for (int j = 0; j < 8; j++) acc[i][j] = 0.f;

    const float* yb = y + (size_t)b * CR_ * THW_;

    for (int k0 = 0; k0 < CR_; k0 += BKG) {
#pragma unroll
        for (int r = 0; r < 2; r++) {
            int idx = tid + 256 * r;
            int kc  = idx >> 5;
            int o4  = (idx & 31) << 2;
            *(float4*)&sA[kc][o4] =
                *(const float4*)&Wrt[(size_t)(k0 + kc) * 256 + o_base + o4];
            *(float4*)&sB[kc][o4] =
                *(const float4*)&yb[(size_t)(k0 + kc) * THW_ + p_base + o4];
        }
        __syncthreads();
#pragma unroll
        for (int kk = 0; kk < BKG; kk++) {
            float4 a0 = *(const float4*)&sA[kk][ty * 4];
            float4 a1 = *(const float4*)&sA[kk][ty * 4 + 64];
            float4 b0 = *(const float4*)&sB[kk][tx * 4];
            float4 b1 = *(const float4*)&sB[kk][tx * 4 + 64];
            float a[8] = {a0.x, a0.y, a0.z, a0.w, a1.x, a1.y, a1.z, a1.w};
            float bb[8] = {b0.x, b0.y, b0.z, b0.w, b1.x, b1.y, b1.z, b1.w};
#pragma unroll
            for (int i = 0; i < 8; i++)
#pragma unroll
                for (int j = 0; j < 8; j++) acc[i][j] += a[i] * bb[j];
        }
        __syncthreads();
    }

#pragma unroll
    for (int i = 0; i < 8; i++) {
        int co = o_base + ty * 4 + (i & 3) + (i >> 2) * 64;
        float sc = gamma[co] * rsqrtf(bn_var[co] + 1e-5f);
        float sh = beta[co] - bn_mean[co] * sc;
        float bi = br[co];
        size_t rowoff = ((size_t)b * C_ + co) * THW_;
#pragma unroll
        for (int jh = 0; jh < 2; jh++) {
            int p = p_base + tx * 4 + jh * 64;
            float4 xv = *(const float4*)&x[rowoff + p];
            float4 v;
            v.x = (acc[i][jh * 4 + 0] + bi) * sc + sh + xv.x;
            v.y = (acc[i][jh * 4 + 1] + bi) * sc + sh + xv.y;
            v.z = (acc[i][jh * 4 + 2] + bi) * sc + sh + xv.z;
            v.w = (acc[i][jh * 4 + 3] + bi) * sc + sh + xv.w;
            *(float4*)&out[rowoff + p] = v;
        }
    }
}

// ---------------------------------------------------------------------------
extern "C" void kernel_launch(void* const* d_in, const int* in_sizes, int n_in,
                              void* d_out, int out_size, void* d_ws, size_t ws_size,
                              hipStream_t stream)
{
    const float* x      = (const float*)d_in[0];
    const float* Wq     = (const float*)d_in[1];
    const float* bq     = (const float*)d_in[2];
    const float* Wk     = (const float*)d_in[3];
    const float* bk     = (const float*)d_in[4];
    const float* Wv     = (const float*)d_in[5];
    const float* bv     = (const float*)d_in[6];
    const float* Wr     = (const float*)d_in[7];
    const float* br     = (const float*)d_in[8];
    const float* gamma  = (const float*)d_in[9];
    const float* beta   = (const float*)d_in[10];
    const float* bn_mean= (const float*)d_in[11];
    const float* bn_var = (const float*)d_in[12];
    float* out = (float*)d_out;

    // d_out doubles as scratch for Q and K (exactly 2 * N_*THW_ floats)
    float* Qb = out;
    float* Kb = out + (size_t)N_ * THW_;

    // workspace layout (floats)
    float* ws   = (float*)d_ws;
    float* Vb   = ws;                                   // 12,845,056
    float* ybuf = Vb   + (size_t)N_ * THW_;             // 12,845,056
    float* Qtk  = ybuf + (size_t)N_ * THW_;             //  3,211,264
    float* Ktk  = Qtk  + (size_t)N_ * T_ * KTOP;        //  3,211,264
    float* attn = Ktk  + (size_t)N_ * T_ * KTOP;        //    262,144
    float* Wt3  = attn + (size_t)N_ * T_ * T_;          //     98,304
    float* Wrt  = Wt3  + 384 * 256;                     //     32,768

    transpose_w<<<dim3(384), 256, 0, stream>>>(Wq, Wk, Wv, Wr, Wt3, Wrt);
    gemm_qkv<<<dim3(98, 3, 8), 256, 0, stream>>>(Wt3, x, bq, bk, bv, Qb, Kb, Vb);
    topk_sort<<<dim3(16384, 2), 256, 0, stream>>>(Qb, Kb, Qtk, Ktk);
    corr_softmax<<<dim3(1024), 256, 0, stream>>>(Qtk, Ktk, attn);
    apply_attn<<<dim3(7, 1024), 256, 0, stream>>>(attn, Vb, ybuf);
    gemm_recon<<<dim3(98, 2, 8), 256, 0, stream>>>(Wrt, ybuf, br, gamma, beta,
                                                   bn_mean, bn_var, x, out);
}

// Round 2
// 691.148 us; speedup vs baseline: 1.9082x; 1.9082x over previous
//
#include <hip/hip_runtime.h>
#include <hip/hip_bf16.h>
#include <cfloat>

// Problem constants
#define B_   8
#define C_   256
#define CR_  128
#define T_   16
#define HW_  784
#define THW_ 12544           // T_*HW_
#define N_   1024            // B_*CR_
#define KTOP 196

#define BKG 16               // GEMM K-tile

// ---------------------------------------------------------------------------
// Kernel 0: transpose weights to k-major for coalesced LDS staging.
// Wt3[c][o3] (o3 in [0,384): Wq rows 0-127, Wk 128-255, Wv 256-383)
// Wrt[cr][co] (128 x 256)
// ---------------------------------------------------------------------------
__global__ __launch_bounds__(256) void transpose_w(
    const float* __restrict__ Wq, const float* __restrict__ Wk,
    const float* __restrict__ Wv, const float* __restrict__ Wr,
    float* __restrict__ Wt3, float* __restrict__ Wrt)
{
    int idx = blockIdx.x * 256 + threadIdx.x;
    if (idx < 384 * 256) {                      // 98304
        int c = idx / 384, o3 = idx % 384;
        int m = o3 >> 7, r = o3 & 127;
        const float* W = (m == 0) ? Wq : (m == 1) ? Wk : Wv;
        Wt3[idx] = W[r * 256 + c];
    }
    if (idx < 128 * 256) {                      // 32768
        int cr = idx >> 8, co = idx & 255;
        Wrt[idx] = Wr[co * 128 + cr];
    }
}

// ---------------------------------------------------------------------------
// Kernel 1: QKV GEMM.  out[b,o,p] = sum_c W[o,c] x[b,c,p] + bias[o]
// 128x128 tile, BK=16, 8x8 microtile per thread (256 threads).
// grid (98, 3, 8): (p_tile, matrix, batch)
// ---------------------------------------------------------------------------
__global__ __launch_bounds__(256) void gemm_qkv(
    const float* __restrict__ Wt3, const float* __restrict__ x,
    const float* __restrict__ bq, const float* __restrict__ bk,
    const float* __restrict__ bv,
    float* __restrict__ Qb, float* __restrict__ Kb, float* __restrict__ Vb)
{
    const int pt = blockIdx.x;
    const int m  = blockIdx.y;
    const int b  = blockIdx.z;
    const int tid = threadIdx.x;
    const int tx = tid & 15, ty = tid >> 4;
    const int p_base = pt * 128;
    const int o_base = m * 128;

    __shared__ float sA[BKG][128];
    __shared__ float sB[BKG][128];

    float acc[8][8];
#pragma unroll
    for (int i = 0; i < 8; i++)
#pragma unroll
        for (int j = 0; j < 8; j++) acc[i][j] = 0.f;

    const float* xb = x + (size_t)b * C_ * THW_;

    for (int k0 = 0; k0 < 256; k0 += BKG) {
#pragma unroll
        for (int r = 0; r < 2; r++) {
            int idx = tid + 256 * r;             // 0..511
            int kc  = idx >> 5;                  // 0..15
            int o4  = (idx & 31) << 2;           // 0..124
            *(float4*)&sA[kc][o4] =
                *(const float4*)&Wt3[(size_t)(k0 + kc) * 384 + o_base + o4];
            *(float4*)&sB[kc][o4] =
                *(const float4*)&xb[(size_t)(k0 + kc) * THW_ + p_base + o4];
        }
        __syncthreads();
#pragma unroll
        for (int kk = 0; kk < BKG; kk++) {
            float4 a0 = *(const float4*)&sA[kk][ty * 4];
            float4 a1 = *(const float4*)&sA[kk][ty * 4 + 64];
            float4 b0 = *(const float4*)&sB[kk][tx * 4];
            float4 b1 = *(const float4*)&sB[kk][tx * 4 + 64];
            float a[8] = {a0.x, a0.y, a0.z, a0.w, a1.x, a1.y, a1.z, a1.w};
            float bb[8] = {b0.x, b0.y, b0.z, b0.w, b1.x, b1.y, b1.z, b1.w};
#pragma unroll
            for (int i = 0; i < 8; i++)
#pragma unroll
                for (int j = 0; j < 8; j++) acc[i][j] += a[i] * bb[j];
        }
        __syncthreads();
    }

    const float* bias = (m == 0) ? bq : (m == 1) ? bk : bv;
    float* outp       = (m == 0) ? Qb : (m == 1) ? Kb : Vb;
#pragma unroll
    for (int i = 0; i < 8; i++) {
        int cr = ty * 4 + (i & 3) + (i >> 2) * 64;
        float bi = bias[cr];
        size_t rowoff = ((size_t)b * CR_ + cr) * THW_;
#pragma unroll
        for (int jh = 0; jh < 2; jh++) {
            int p = p_base + tx * 4 + jh * 64;
            float4 v;
            v.x = acc[i][jh * 4 + 0] + bi;
            v.y = acc[i][jh * 4 + 1] + bi;
            v.z = acc[i][jh * 4 + 2] + bi;
            v.w = acc[i][jh * 4 + 3] + bi;
            *(float4*)&outp[rowoff + p] = v;
        }
    }
}

// ---------------------------------------------------------------------------
// Kernel 2: per-row descending bitonic sort, fully in registers, one wave per
// row. Element index i = lane*16 + r (lane-major), 784 padded to 1024 with
// -FLT_MAX. 34 of 55 bitonic phases are pure in-register (j<16); 21 phases
// use __shfl_xor. No LDS, no barriers. 784 = 49 lanes * 16 -> exact float4
// tiling; top-196 output = lanes 0..12.
// grid (8192): 4 waves/block, wave g handles row g (g<16384 -> Q, else K).
// ---------------------------------------------------------------------------
__global__ __launch_bounds__(256) void topk_sort_wave(
    const float* __restrict__ Qb, const float* __restrict__ Kb,
    float* __restrict__ Qtk, float* __restrict__ Ktk)
{
    const int wave = threadIdx.x >> 6;
    const int lane = threadIdx.x & 63;
    const int gw   = blockIdx.x * 4 + wave;      // 0..32767
    const int mat  = gw >> 14;                   // 0: Q, 1: K
    const int row  = gw & 16383;
    const float* src = ((mat == 0) ? Qb : Kb) + (size_t)row * HW_;
    float* dst       = ((mat == 0) ? Qtk : Ktk) + (size_t)row * KTOP;

    float v[16];
    if (lane < 49) {
        const float4* s4 = (const float4*)(src + lane * 16);
#pragma unroll
        for (int q = 0; q < 4; q++) {
            float4 t = s4[q];
            v[q * 4 + 0] = t.x; v[q * 4 + 1] = t.y;
            v[q * 4 + 2] = t.z; v[q * 4 + 3] = t.w;
        }
    } else {
#pragma unroll
        for (int r = 0; r < 16; r++) v[r] = -FLT_MAX;
    }

#pragma unroll
    for (int k = 2; k <= 1024; k <<= 1) {
#pragma unroll
        for (int j = k >> 1; j >= 1; j >>= 1) {
            if (j >= 16) {
                // cross-lane exchange, same register
                const int jl = j >> 4;
                const bool up      = ((lane & (k >> 4)) == 0); // k>=32 here
                const bool isLower = ((lane & jl) == 0);
                const bool keepMax = (up == isLower);
#pragma unroll
                for (int r = 0; r < 16; r++) {
                    float other = __shfl_xor(v[r], jl, 64);
                    float mx = fmaxf(v[r], other);
                    float mn = fminf(v[r], other);
                    v[r] = keepMax ? mx : mn;
                }
            } else {
                // in-register exchange between r and r|j
#pragma unroll
                for (int r = 0; r < 16; r++) {
                    if ((r & j) == 0) {
                        const int rb = r | j;
                        // direction: i = lane*16 + r, up = ((i & k) == 0)
                        const bool up = (k >= 16) ? ((lane & (k >> 4)) == 0)
                                                  : ((r & k) == 0);
                        float a = v[r], b = v[rb];
                        float hi = fmaxf(a, b), lo = fminf(a, b);
                        v[r]  = up ? hi : lo;
                        v[rb] = up ? lo : hi;
                    }
                }
            }
        }
    }

    // store top 196 = elements 0..195 = lanes 0..11 fully + lane 12 regs 0..3
    if (lane < 12) {
        float4* d4 = (float4*)(dst + lane * 16);
#pragma unroll
        for (int q = 0; q < 4; q++) {
            float4 t;
            t.x = v[q * 4 + 0]; t.y = v[q * 4 + 1];
            t.z = v[q * 4 + 2]; t.w = v[q * 4 + 3];
            d4[q] = t;
        }
    } else if (lane == 12) {
        float4 t;
        t.x = v[0]; t.y = v[1]; t.z = v[2]; t.w = v[3];
        *(float4*)(dst + 192) = t;
    }
}

// ---------------------------------------------------------------------------
// Kernel 3: corr[n,t,s] = dot(Qtk[n,t,:], Ktk[n,s,:]) then softmax over s.
// grid (1024), block 256 (one (t,s) pair per thread)
// ---------------------------------------------------------------------------
__global__ __launch_bounds__(256) void corr_softmax(
    const float* __restrict__ Qtk, const float* __restrict__ Ktk,
    float* __restrict__ attn)
{
    const int n = blockIdx.x;
    __shared__ float qs[T_ * KTOP];
    __shared__ float ks[T_ * KTOP];
    __shared__ float cm[T_][T_ + 1];
    __shared__ float mx[T_], sm[T_];
    const int tid = threadIdx.x;

    for (int i = tid; i < T_ * KTOP; i += 256) {
        qs[i] = Qtk[(size_t)n * T_ * KTOP + i];
        ks[i] = Ktk[(size_t)n * T_ * KTOP + i];
    }
    __syncthreads();

    const int t = tid >> 4, sidx = tid & 15;
    const float* qr = &qs[t * KTOP];
    const float* kr = &ks[sidx * KTOP];
    float c = 0.f;
#pragma unroll 4
    for (int i = 0; i < KTOP; i++) c += qr[i] * kr[i];
    cm[t][sidx] = c;
    __syncthreads();

    if (tid < T_) {
        float m = cm[tid][0];
        for (int i = 1; i < T_; i++) m = fmaxf(m, cm[tid][i]);
        mx[tid] = m;
    }
    __syncthreads();
    float e = expf(c - mx[t]);
    cm[t][sidx] = e;
    __syncthreads();
    if (tid < T_) {
        float ssum = 0.f;
        for (int i = 0; i < T_; i++) ssum += cm[tid][i];
        sm[tid] = ssum;
    }
    __syncthreads();
    attn[(size_t)n * 256 + tid] = e / sm[t];
}

// ---------------------------------------------------------------------------
// Kernel 4: y[n,t,p] = sum_s attn[n,t,s] * V[n,s,p]
// grid (7, 1024): p-chunk of 112, n
// ---------------------------------------------------------------------------
__global__ __launch_bounds__(256) void apply_attn(
    const float* __restrict__ attn, const float* __restrict__ V,
    float* __restrict__ y)
{
    const int pc = blockIdx.x;
    const int n  = blockIdx.y;
    __shared__ float at[256];
    __shared__ float vt[T_][112];
    const int tid = threadIdx.x;

    at[tid] = attn[(size_t)n * 256 + tid];
    const int p0 = pc * 112;
    for (int idx = tid; idx < T_ * 112; idx += 256) {
        int s = idx / 112, pp = idx % 112;
        vt[s][pp] = V[(size_t)n * THW_ + s * HW_ + p0 + pp];
    }
    __syncthreads();

    for (int idx = tid; idx < T_ * 112; idx += 256) {
        int t = idx / 112, pp = idx % 112;
        float a = 0.f;
#pragma unroll
        for (int s = 0; s < T_; s++) a += at[t * 16 + s] * vt[s][pp];
        y[(size_t)n * THW_ + t * HW_ + p0 + pp] = a;
    }
}

// ---------------------------------------------------------------------------
// Kernel 5: out[b,co,p] = scale*(sum_cr Wr[co,cr] y[b,cr,p] + br) + shift + x
// grid (98, 2, 8)
// ---------------------------------------------------------------------------
__global__ __launch_bounds__(256) void gemm_recon(
    const float* __restrict__ Wrt, const float* __restrict__ y,
    const float* __restrict__ br, const float* __restrict__ gamma,
    const float* __restrict__ beta, const float* __restrict__ bn_mean,
    const float* __restrict__ bn_var, const float* __restrict__ x,
    float* __restrict__ out)
{
    const int pt = blockIdx.x;
    const int ot = blockIdx.y;
    const int b  = blockIdx.z;
    const int tid = threadIdx.x;
    const int tx = tid & 15, ty = tid >> 4;
    const int p_base = pt * 128;
    const int o_base = ot * 128;

    __shared__ float sA[BKG][128];
    __shared__ float sB[BKG][128];

    float acc[8][8];
#pragma unroll
    for (int i = 0; i < 8; i++)
#pragma unroll
        for (int j = 0; j < 8; j++) acc[i][j] = 0.f;

    const float* yb = y + (size_t)b * CR_ * THW_;

    for (int k0 = 0; k0 < CR_; k0 += BKG) {
#pragma unroll
        for (int r = 0; r < 2; r++) {
            int idx = tid + 256 * r;
            int kc  = idx >> 5;
            int o4  = (idx & 31) << 2;
            *(float4*)&sA[kc][o4] =
                *(const float4*)&Wrt[(size_t)(k0 + kc) * 256 + o_base + o4];
            *(float4*)&sB[kc][o4] =
                *(const float4*)&yb[(size_t)(k0 + kc) * THW_ + p_base + o4];
        }
        __syncthreads();
#pragma unroll
        for (int kk = 0; kk < BKG; kk++) {
            float4 a0 = *(const float4*)&sA[kk][ty * 4];
            float4 a1 = *(const float4*)&sA[kk][ty * 4 + 64];
            float4 b0 = *(const float4*)&sB[kk][tx * 4];
            float4 b1 = *(const float4*)&sB[kk][tx * 4 + 64];
            float a[8] = {a0.x, a0.y, a0.z, a0.w, a1.x, a1.y, a1.z, a1.w};
            float bb[8] = {b0.x, b0.y, b0.z, b0.w, b1.x, b1.y, b1.z, b1.w};
#pragma unroll
            for (int i = 0; i < 8; i++)
#pragma unroll
                for (int j = 0; j < 8; j++) acc[i][j] += a[i] * bb[j];
        }
        __syncthreads();
    }

#pragma unroll
    for (int i = 0; i < 8; i++) {
        int co = o_base + ty * 4 + (i & 3) + (i >> 2) * 64;
        float sc = gamma[co] * rsqrtf(bn_var[co] + 1e-5f);
        float sh = beta[co] - bn_mean[co] * sc;
        float bi = br[co];
        size_t rowoff = ((size_t)b * C_ + co) * THW_;
#pragma unroll
        for (int jh = 0; jh < 2; jh++) {
            int p = p_base + tx * 4 + jh * 64;
            float4 xv = *(const float4*)&x[rowoff + p];
            float4 v;
            v.x = (acc[i][jh * 4 + 0] + bi) * sc + sh + xv.x;
            v.y = (acc[i][jh * 4 + 1] + bi) * sc + sh + xv.y;
            v.z = (acc[i][jh * 4 + 2] + bi) * sc + sh + xv.z;
            v.w = (acc[i][jh * 4 + 3] + bi) * sc + sh + xv.w;
            *(float4*)&out[rowoff + p] = v;
        }
    }
}

// ---------------------------------------------------------------------------
extern "C" void kernel_launch(void* const* d_in, const int* in_sizes, int n_in,
                              void* d_out, int out_size, void* d_ws, size_t ws_size,
                              hipStream_t stream)
{
    const float* x      = (const float*)d_in[0];
    const float* Wq     = (const float*)d_in[1];
    const float* bq     = (const float*)d_in[2];
    const float* Wk     = (const float*)d_in[3];
    const float* bk     = (const float*)d_in[4];
    const float* Wv     = (const float*)d_in[5];
    const float* bv     = (const float*)d_in[6];
    const float* Wr     = (const float*)d_in[7];
    const float* br     = (const float*)d_in[8];
    const float* gamma  = (const float*)d_in[9];
    const float* beta   = (const float*)d_in[10];
    const float* bn_mean= (const float*)d_in[11];
    const float* bn_var = (const float*)d_in[12];
    float* out = (float*)d_out;

    // d_out doubles as scratch for Q and K (exactly 2 * N_*THW_ floats)
    float* Qb = out;
    float* Kb = out + (size_t)N_ * THW_;

    // workspace layout (floats)
    float* ws   = (float*)d_ws;
    float* Vb   = ws;                                   // 12,845,056
    float* ybuf = Vb   + (size_t)N_ * THW_;             // 12,845,056
    float* Qtk  = ybuf + (size_t)N_ * THW_;             //  3,211,264
    float* Ktk  = Qtk  + (size_t)N_ * T_ * KTOP;        //  3,211,264
    float* attn = Ktk  + (size_t)N_ * T_ * KTOP;        //    262,144
    float* Wt3  = attn + (size_t)N_ * T_ * T_;          //     98,304
    float* Wrt  = Wt3  + 384 * 256;                     //     32,768

    transpose_w<<<dim3(384), 256, 0, stream>>>(Wq, Wk, Wv, Wr, Wt3, Wrt);
    gemm_qkv<<<dim3(98, 3, 8), 256, 0, stream>>>(Wt3, x, bq, bk, bv, Qb, Kb, Vb);
    topk_sort_wave<<<dim3(8192), 256, 0, stream>>>(Qb, Kb, Qtk, Ktk);
    corr_softmax<<<dim3(1024), 256, 0, stream>>>(Qtk, Ktk, attn);
    apply_attn<<<dim3(7, 1024), 256, 0, stream>>>(attn, Vb, ybuf);
    gemm_recon<<<dim3(98, 2, 8), 256, 0, stream>>>(Wrt, ybuf, br, gamma, beta,
                                                   bn_mean, bn_var, x, out);
}

// Round 4
// 575.286 us; speedup vs baseline: 2.2926x; 1.2014x over previous
//
#include <hip/hip_runtime.h>
#include <hip/hip_bf16.h>
#include <cfloat>

// Problem constants
#define B_   8
#define C_   256
#define CR_  128
#define T_   16
#define HW_  784
#define THW_ 12544           // T_*HW_
#define N_   1024            // B_*CR_
#define KTOP 196

typedef __attribute__((ext_vector_type(8))) short short8;
typedef __attribute__((ext_vector_type(4))) float float4_;

// bf16 helpers (RN-even), header-independent
__device__ __forceinline__ unsigned short f2bf(float x) {
    unsigned int u = __float_as_uint(x);
    unsigned int r = u + 0x7fffu + ((u >> 16) & 1u);
    return (unsigned short)(r >> 16);
}
__device__ __forceinline__ float bf2f(unsigned short s) {
    return __uint_as_float(((unsigned int)s) << 16);
}

// ---------------------------------------------------------------------------
// Kernel 0: prep.
//  - Whi/Wlo [o=384][k=256] bf16 hi/lo split of {Wq,Wk,Wv} (native k-major)
//  - Wrbf   [co=256][cr=128] bf16 of Wr (native k-major)
//  - bias3[384] = bq|bk|bv
//  - A1[co]=gamma*rsqrt(var+eps), A2[co]=br*A1 + beta - mean*A1
// ---------------------------------------------------------------------------
__global__ __launch_bounds__(256) void prep(
    const float* __restrict__ Wq, const float* __restrict__ Wk,
    const float* __restrict__ Wv, const float* __restrict__ Wr,
    const float* __restrict__ bq, const float* __restrict__ bk,
    const float* __restrict__ bv, const float* __restrict__ br,
    const float* __restrict__ gamma, const float* __restrict__ beta,
    const float* __restrict__ bn_mean, const float* __restrict__ bn_var,
    unsigned short* __restrict__ Whi, unsigned short* __restrict__ Wlo,
    unsigned short* __restrict__ Wrbf, float* __restrict__ bias3,
    float* __restrict__ A1, float* __restrict__ A2)
{
    int idx = blockIdx.x * 256 + threadIdx.x;
    if (idx < 384 * 256) {
        int o = idx >> 8, k = idx & 255;
        int m = o >> 7, r = o & 127;
        const float* W = (m == 0) ? Wq : (m == 1) ? Wk : Wv;
        float v = W[r * 256 + k];
        unsigned short h = f2bf(v);
        Whi[idx] = h;
        Wlo[idx] = f2bf(v - bf2f(h));
    }
    if (idx < 256 * 128) {
        Wrbf[idx] = f2bf(Wr[idx]);
    }
    if (idx < 384) {
        bias3[idx] = (idx < 128) ? bq[idx] : (idx < 256) ? bk[idx - 128] : bv[idx - 256];
    }
    if (idx < 256) {
        float sc = gamma[idx] * rsqrtf(bn_var[idx] + 1e-5f);
        A1[idx] = sc;
        A2[idx] = br[idx] * sc + beta[idx] - bn_mean[idx] * sc;
    }
}

// ---------------------------------------------------------------------------
// Kernel 1: QKV GEMM via bf16x3 MFMA (fp32-accurate).
// out[b,o,p] = sum_c W[o,c] x[b,c,p] + bias[o],  o in [0,384)
// Block: M=384 x N=64 tile, 4 waves (wave w: m in [96w,96w+96)).
// A (weights hi/lo) staged in LDS per k-step; B (x) fragments loaded directly
// from global fp32 with in-register hi/lo split.
// grid (196, 8): (p-tile of 64, batch)
// ---------------------------------------------------------------------------
__global__ __launch_bounds__(256) void gemm_qkv_mfma(
    const unsigned short* __restrict__ Whi, const unsigned short* __restrict__ Wlo,
    const float* __restrict__ x, const float* __restrict__ bias3,
    float* __restrict__ Qb, float* __restrict__ Kb, float* __restrict__ Vb)
{
    const int tid  = threadIdx.x;
    const int wave = tid >> 6;
    const int lane = tid & 63;
    const int quad = lane >> 4;
    const int l16  = lane & 15;
    const int p0   = blockIdx.x * 64;
    const int b    = blockIdx.y;
    const int mW   = wave * 96;

    // LDS: A tile [var][m=384][k=32] padded to 40 shorts (80B rows, 16B mult)
    __shared__ unsigned short Ald[2][384][40];

    float4_ acc[6][4];
#pragma unroll
    for (int i = 0; i < 6; i++)
#pragma unroll
        for (int j = 0; j < 4; j++) acc[i][j] = (float4_)0.f;

    const float* xb = x + (size_t)b * C_ * THW_;

    for (int k0 = 0; k0 < 256; k0 += 32) {
        // --- stage A hi/lo: per var, 1536 chunks of 8 shorts (16B) ---
#pragma unroll
        for (int var = 0; var < 2; var++) {
            const unsigned short* Wsrc = var ? Wlo : Whi;
#pragma unroll
            for (int it = 0; it < 6; it++) {
                int cc = tid + it * 256;         // 0..1535
                int o  = cc >> 2;                // 0..383
                int j  = cc & 3;                 // 0..3
                *(uint4*)&Ald[var][o][j * 8] =
                    *(const uint4*)&Wsrc[(size_t)o * 256 + k0 + j * 8];
            }
        }
        __syncthreads();

        // --- B fragments: direct global loads + hi/lo split ---
        short8 Bh[4], Bl[4];
#pragma unroll
        for (int nf = 0; nf < 4; nf++) {
            const float* bp = xb + (size_t)(k0 + quad * 8) * THW_ + p0 + nf * 16 + l16;
#pragma unroll
            for (int jj = 0; jj < 8; jj++) {
                float v = bp[(size_t)jj * THW_];
                unsigned short h = f2bf(v);
                Bh[nf][jj] = (short)h;
                Bl[nf][jj] = (short)f2bf(v - bf2f(h));
            }
        }

        // --- MFMA: 6 m-frags x 4 n-frags x 3 products ---
#pragma unroll
        for (int mf = 0; mf < 6; mf++) {
            short8 Ah = *(const short8*)&Ald[0][mW + mf * 16 + l16][quad * 8];
            short8 Al = *(const short8*)&Ald[1][mW + mf * 16 + l16][quad * 8];
#pragma unroll
            for (int nf = 0; nf < 4; nf++) {
                acc[mf][nf] = __builtin_amdgcn_mfma_f32_16x16x32_bf16(Al, Bh[nf], acc[mf][nf], 0, 0, 0);
                acc[mf][nf] = __builtin_amdgcn_mfma_f32_16x16x32_bf16(Ah, Bl[nf], acc[mf][nf], 0, 0, 0);
                acc[mf][nf] = __builtin_amdgcn_mfma_f32_16x16x32_bf16(Ah, Bh[nf], acc[mf][nf], 0, 0, 0);
            }
        }
        __syncthreads();
    }

    // --- epilogue: o = mW + mf*16 + quad*4 + r, p = p0 + nf*16 + l16 ---
#pragma unroll
    for (int mf = 0; mf < 6; mf++) {
#pragma unroll
        for (int r = 0; r < 4; r++) {
            int oo  = mW + mf * 16 + quad * 4 + r;
            int mat = oo >> 7;
            int cr  = oo & 127;
            float bi = bias3[oo];
            float* dst = ((mat == 0) ? Qb : (mat == 1) ? Kb : Vb)
                         + ((size_t)(b * 128 + cr)) * THW_ + p0 + l16;
#pragma unroll
            for (int nf = 0; nf < 4; nf++)
                dst[nf * 16] = acc[mf][nf][r] + bi;
        }
    }
}

// ---------------------------------------------------------------------------
// Kernel 2: per-row descending bitonic sort, fully in registers, one wave per
// row (unchanged).
// ---------------------------------------------------------------------------
__global__ __launch_bounds__(256) void topk_sort_wave(
    const float* __restrict__ Qb, const float* __restrict__ Kb,
    float* __restrict__ Qtk, float* __restrict__ Ktk)
{
    const int wave = threadIdx.x >> 6;
    const int lane = threadIdx.x & 63;
    const int gw   = blockIdx.x * 4 + wave;      // 0..32767
    const int mat  = gw >> 14;                   // 0: Q, 1: K
    const int row  = gw & 16383;
    const float* src = ((mat == 0) ? Qb : Kb) + (size_t)row * HW_;
    float* dst       = ((mat == 0) ? Qtk : Ktk) + (size_t)row * KTOP;

    float v[16];
    if (lane < 49) {
        const float4* s4 = (const float4*)(src + lane * 16);
#pragma unroll
        for (int q = 0; q < 4; q++) {
            float4 t = s4[q];
            v[q * 4 + 0] = t.x; v[q * 4 + 1] = t.y;
            v[q * 4 + 2] = t.z; v[q * 4 + 3] = t.w;
        }
    } else {
#pragma unroll
        for (int r = 0; r < 16; r++) v[r] = -FLT_MAX;
    }

#pragma unroll
    for (int k = 2; k <= 1024; k <<= 1) {
#pragma unroll
        for (int j = k >> 1; j >= 1; j >>= 1) {
            if (j >= 16) {
                const int jl = j >> 4;
                const bool up      = ((lane & (k >> 4)) == 0);
                const bool isLower = ((lane & jl) == 0);
                const bool keepMax = (up == isLower);
#pragma unroll
                for (int r = 0; r < 16; r++) {
                    float other = __shfl_xor(v[r], jl, 64);
                    float mx = fmaxf(v[r], other);
                    float mn = fminf(v[r], other);
                    v[r] = keepMax ? mx : mn;
                }
            } else {
#pragma unroll
                for (int r = 0; r < 16; r++) {
                    if ((r & j) == 0) {
                        const int rb = r | j;
                        const bool up = (k >= 16) ? ((lane & (k >> 4)) == 0)
                                                  : ((r & k) == 0);
                        float a = v[r], b = v[rb];
                        float hi = fmaxf(a, b), lo = fminf(a, b);
                        v[r]  = up ? hi : lo;
                        v[rb] = up ? lo : hi;
                    }
                }
            }
        }
    }

    if (lane < 12) {
        float4* d4 = (float4*)(dst + lane * 16);
#pragma unroll
        for (int q = 0; q < 4; q++) {
            float4 t;
            t.x = v[q * 4 + 0]; t.y = v[q * 4 + 1];
            t.z = v[q * 4 + 2]; t.w = v[q * 4 + 3];
            d4[q] = t;
        }
    } else if (lane == 12) {
        float4 t;
        t.x = v[0]; t.y = v[1]; t.z = v[2]; t.w = v[3];
        *(float4*)(dst + 192) = t;
    }
}

// ---------------------------------------------------------------------------
// Kernel 3: corr + softmax (unchanged).
// ---------------------------------------------------------------------------
__global__ __launch_bounds__(256) void corr_softmax(
    const float* __restrict__ Qtk, const float* __restrict__ Ktk,
    float* __restrict__ attn)
{
    const int n = blockIdx.x;
    __shared__ float qs[T_ * KTOP];
    __shared__ float ks[T_ * KTOP];
    __shared__ float cm[T_][T_ + 1];
    __shared__ float mx[T_], sm[T_];
    const int tid = threadIdx.x;

    for (int i = tid; i < T_ * KTOP; i += 256) {
        qs[i] = Qtk[(size_t)n * T_ * KTOP + i];
        ks[i] = Ktk[(size_t)n * T_ * KTOP + i];
    }
    __syncthreads();

    const int t = tid >> 4, sidx = tid & 15;
    const float* qr = &qs[t * KTOP];
    const float* kr = &ks[sidx * KTOP];
    float c = 0.f;
#pragma unroll 4
    for (int i = 0; i < KTOP; i++) c += qr[i] * kr[i];
    cm[t][sidx] = c;
    __syncthreads();

    if (tid < T_) {
        float m = cm[tid][0];
        for (int i = 1; i < T_; i++) m = fmaxf(m, cm[tid][i]);
        mx[tid] = m;
    }
    __syncthreads();
    float e = expf(c - mx[t]);
    cm[t][sidx] = e;
    __syncthreads();
    if (tid < T_) {
        float ssum = 0.f;
        for (int i = 0; i < T_; i++) ssum += cm[tid][i];
        sm[tid] = ssum;
    }
    __syncthreads();
    attn[(size_t)n * 256 + tid] = e / sm[t];
}

// ---------------------------------------------------------------------------
// Kernel 4: apply attention, output TRANSPOSED bf16: yT[b][t*784+p][cr].
// grid (49, 8): (p-window of 16, batch). cr processed in chunks of 16.
// ---------------------------------------------------------------------------
__global__ __launch_bounds__(256) void apply_attn_T(
    const float* __restrict__ attn, const float* __restrict__ V,
    unsigned short* __restrict__ yT)
{
    const int pc = blockIdx.x;      // p-window
    const int b  = blockIdx.y;
    const int p0 = pc * 16;
    const int tid = threadIdx.x;
    const int crl = tid & 15;       // local cr
    const int g   = tid >> 4;       // 0..15, handles 16 (t,p) pairs

    __shared__ float at[16][257];   // [crl][t*16+s]
    __shared__ float vt[16][257];   // [crl][s*16+p]

    for (int chunk = 0; chunk < 8; chunk++) {
        const int crbase = chunk * 16;
        for (int i = tid; i < 16 * 256; i += 256) {
            int cr = i >> 8, ts = i & 255;
            at[cr][ts] = attn[((size_t)(b * 128 + crbase + cr)) * 256 + ts];
        }
        for (int i = tid; i < 16 * 256; i += 256) {
            int cr = i >> 8, s = (i >> 4) & 15, p = i & 15;
            vt[cr][s * 16 + p] =
                V[((size_t)(b * 128 + crbase + cr)) * THW_ + s * HW_ + p0 + p];
        }
        __syncthreads();

        const int cr = crbase + crl;
#pragma unroll
        for (int u = 0; u < 16; u++) {
            int idx = g * 16 + u;       // 0..255
            int t = idx >> 4, p = idx & 15;
            float sum = 0.f;
#pragma unroll
            for (int s = 0; s < 16; s++)
                sum += at[crl][t * 16 + s] * vt[crl][s * 16 + p];
            yT[((size_t)b * THW_ + t * HW_ + p0 + p) * 128 + cr] = f2bf(sum);
        }
        __syncthreads();
    }
}

// ---------------------------------------------------------------------------
// Kernel 5: reconstruct GEMM via bf16 MFMA, fused BN + residual (unchanged).
// grid (196, 8)
// ---------------------------------------------------------------------------
__global__ __launch_bounds__(256) void gemm_recon_mfma(
    const unsigned short* __restrict__ Wrbf, const unsigned short* __restrict__ yT,
    const float* __restrict__ A1, const float* __restrict__ A2,
    const float* __restrict__ x, float* __restrict__ out)
{
    const int tid  = threadIdx.x;
    const int wave = tid >> 6;
    const int lane = tid & 63;
    const int quad = lane >> 4;
    const int l16  = lane & 15;
    const int p0   = blockIdx.x * 64;
    const int b    = blockIdx.y;
    const int mW   = wave * 64;

    float4_ acc[4][4];
#pragma unroll
    for (int i = 0; i < 4; i++)
#pragma unroll
        for (int j = 0; j < 4; j++) acc[i][j] = (float4_)0.f;

    const unsigned short* yTb = yT + (size_t)b * THW_ * 128;

#pragma unroll
    for (int k0 = 0; k0 < 128; k0 += 32) {
        short8 Bf[4];
#pragma unroll
        for (int nf = 0; nf < 4; nf++)
            Bf[nf] = *(const short8*)&yTb[(size_t)(p0 + nf * 16 + l16) * 128 + k0 + quad * 8];
#pragma unroll
        for (int mf = 0; mf < 4; mf++) {
            short8 Af = *(const short8*)&Wrbf[(size_t)(mW + mf * 16 + l16) * 128 + k0 + quad * 8];
#pragma unroll
            for (int nf = 0; nf < 4; nf++)
                acc[mf][nf] = __builtin_amdgcn_mfma_f32_16x16x32_bf16(Af, Bf[nf], acc[mf][nf], 0, 0, 0);
        }
    }

#pragma unroll
    for (int mf = 0; mf < 4; mf++) {
#pragma unroll
        for (int r = 0; r < 4; r++) {
            int co = mW + mf * 16 + quad * 4 + r;
            float sc = A1[co], sh = A2[co];
            size_t base = ((size_t)b * 256 + co) * THW_ + p0 + l16;
#pragma unroll
            for (int nf = 0; nf < 4; nf++) {
                float xv = x[base + nf * 16];
                out[base + nf * 16] = acc[mf][nf][r] * sc + sh + xv;
            }
        }
    }
}

// ---------------------------------------------------------------------------
extern "C" void kernel_launch(void* const* d_in, const int* in_sizes, int n_in,
                              void* d_out, int out_size, void* d_ws, size_t ws_size,
                              hipStream_t stream)
{
    const float* x      = (const float*)d_in[0];
    const float* Wq     = (const float*)d_in[1];
    const float* bq     = (const float*)d_in[2];
    const float* Wk     = (const float*)d_in[3];
    const float* bk     = (const float*)d_in[4];
    const float* Wv     = (const float*)d_in[5];
    const float* bv     = (const float*)d_in[6];
    const float* Wr     = (const float*)d_in[7];
    const float* br     = (const float*)d_in[8];
    const float* gamma  = (const float*)d_in[9];
    const float* beta   = (const float*)d_in[10];
    const float* bn_mean= (const float*)d_in[11];
    const float* bn_var = (const float*)d_in[12];
    float* out = (float*)d_out;

    // d_out doubles as scratch for Q and K (exactly 2 * N_*THW_ floats)
    float* Qb = out;
    float* Kb = out + (size_t)N_ * THW_;

    // workspace layout
    char* ws = (char*)d_ws;
    float* Vb            = (float*)ws;                       ws += (size_t)N_ * THW_ * 4;      // 51.4 MB
    unsigned short* yT   = (unsigned short*)ws;              ws += (size_t)N_ * THW_ * 2;      // 25.7 MB
    float* Qtk           = (float*)ws;                       ws += (size_t)N_ * T_ * KTOP * 4;
    float* Ktk           = (float*)ws;                       ws += (size_t)N_ * T_ * KTOP * 4;
    float* attn          = (float*)ws;                       ws += (size_t)N_ * T_ * T_ * 4;
    unsigned short* Whi  = (unsigned short*)ws;              ws += 384 * 256 * 2;
    unsigned short* Wlo  = (unsigned short*)ws;              ws += 384 * 256 * 2;
    unsigned short* Wrbf = (unsigned short*)ws;              ws += 256 * 128 * 2;
    float* bias3         = (float*)ws;                       ws += 384 * 4;
    float* A1            = (float*)ws;                       ws += 256 * 4;
    float* A2            = (float*)ws;                       ws += 256 * 4;

    prep<<<dim3(384), 256, 0, stream>>>(Wq, Wk, Wv, Wr, bq, bk, bv, br,
                                        gamma, beta, bn_mean, bn_var,
                                        Whi, Wlo, Wrbf, bias3, A1, A2);
    gemm_qkv_mfma<<<dim3(196, 8), 256, 0, stream>>>(Whi, Wlo, x, bias3, Qb, Kb, Vb);
    topk_sort_wave<<<dim3(8192), 256, 0, stream>>>(Qb, Kb, Qtk, Ktk);
    corr_softmax<<<dim3(1024), 256, 0, stream>>>(Qtk, Ktk, attn);
    apply_attn_T<<<dim3(49, 8), 256, 0, stream>>>(attn, Vb, yT);
    gemm_recon_mfma<<<dim3(196, 8), 256, 0, stream>>>(Wrbf, yT, A1, A2, x, out);
}